// Round 12
// baseline (337.196 us; speedup 1.0000x reference)
//
#include <hip/hip_runtime.h>
#include <hip/hip_bf16.h>
#include <hip/hip_fp16.h>

#define N_USER 150000
#define M_ITEM 30000
#define N_NODES 180000
#define E2 1200000
#define BATCH 1024
#define AUX_W 10246
#define KP_G 32
#define KP_D 2208
#define KP_A 8064
#define NBKT 265       // 147 user buckets (1024 rows) + 118 item buckets (256 rows)
#define WT_BLKS 2576   // ((KP_G+KP_D+KP_A)*64 + 255)/256
#define BCNT_BLKS 293  // (E2 + 4095)/4096

typedef __attribute__((ext_vector_type(8))) short short8;
typedef __attribute__((ext_vector_type(4))) float f32x4;

__device__ __forceinline__ int bucket_of(int r) {
    return r < N_USER ? (r >> 10) : 147 + ((r - N_USER) >> 8);
}

// inline dtype detect (wave-uniform): bf16 data reads small; f32-as-bf16 huge.
__device__ __forceinline__ int detect_f32(const void* probe) {
    float v = __bfloat162float(((const __hip_bfloat16*)probe)[threadIdx.x & 63]);
    unsigned long long m = __ballot(!(fabsf(v) < 1000.0f));
    return __popcll(m) > 8;
}

// ---------------- fused prep: table cvt + Wt pack + bucket counts ----------
struct CvtSeg { const void* src; float* dst; int n; int blk0; };
struct CvtBatch { CvtSeg seg[16]; };

__global__ void __launch_bounds__(256) k_prep(CvtBatch cb, int cvtBlks,
                                              const void* Wg, const void* Wd, const void* Wa,
                                              unsigned short* WtG, unsigned short* WtD, unsigned short* WtA,
                                              const int* __restrict__ grow, int* __restrict__ bucket_tot,
                                              const void* probe) {
    int blk = blockIdx.x, tid = threadIdx.x;
    if (blk < cvtBlks) {                       // --- small-table f32 conversion
        int isf32 = detect_f32(probe);
        int si = 0;
        #pragma unroll
        for (int i = 0; i < 16; ++i) if (blk >= cb.seg[i].blk0) si = i;
        const CvtSeg sg = cb.seg[si];
        int i = (blk - sg.blk0) * 256 + tid;
        if (i >= sg.n) return;
        if (isf32) sg.dst[i] = ((const float*)sg.src)[i];
        else       sg.dst[i] = __bfloat162float(((const __hip_bfloat16*)sg.src)[i]);
        return;
    }
    if (blk < cvtBlks + WT_BLKS) {             // --- Wt B-fragment pack
        int isf32 = detect_f32(probe);
        int t = (blk - cvtBlks) * 256 + tid;
        if (t >= (KP_G + KP_D + KP_A) * 64) return;
        int kp = t >> 6, n = t & 63;
        int k, K; const void* src; unsigned short* dst;
        if (kp < KP_G)              { k = kp;               K = 25;   src = Wg; dst = WtG; }
        else if (kp < KP_G + KP_D)  { k = kp - KP_G;        K = 2186; src = Wd; dst = WtD; }
        else                        { k = kp - KP_G - KP_D; K = 8030; src = Wa; dst = WtA; }
        unsigned short v = 0;
        if (k < K) {
            if (isf32) {
                __hip_bfloat16 h = __float2bfloat16(((const float*)src)[(size_t)k * 64 + n]);
                v = *(unsigned short*)&h;
            } else {
                v = ((const unsigned short*)src)[(size_t)k * 64 + n];
            }
        }
        dst[(((size_t)(k >> 5) * 64 + n) * 4 + ((k >> 3) & 3)) * 8 + (k & 7)] = v;
        return;
    }
    // --- bucket counts (bucket_tot pre-zeroed by memset before this launch)
    __shared__ int h[NBKT];
    for (int i = tid; i < NBKT; i += 256) h[i] = 0;
    __syncthreads();
    int idx0 = (blk - cvtBlks - WT_BLKS) * 4096;
    #pragma unroll
    for (int k = 0; k < 16; ++k) {
        int i = idx0 + k * 256 + tid;
        if (i < E2) atomicAdd(&h[bucket_of(grow[i])], 1);
    }
    __syncthreads();
    for (int i = tid; i < NBKT; i += 256) if (h[i]) atomicAdd(&bucket_tot[i], h[i]);
}

// ---------------- bucket scan ----------------
__global__ void __launch_bounds__(512) k_bscan(const int* __restrict__ bucket_tot,
                                               int* __restrict__ bucket_base,
                                               int* __restrict__ bucketcur) {
    __shared__ int s[512];
    int tid = threadIdx.x;
    s[tid] = (tid < NBKT) ? bucket_tot[tid] : 0;
    __syncthreads();
    for (int off = 1; off < 512; off <<= 1) {
        int v = (tid >= off) ? s[tid - off] : 0;
        __syncthreads();
        s[tid] += v;
        __syncthreads();
    }
    int excl = tid ? s[tid - 1] : 0;
    bucket_base[tid] = excl;                 // bucket_base[NBKT] = E2
    if (tid < NBKT) bucketcur[tid] = excl;
}

// ---------------- P1: bin edges into NBKT row-range buckets ----------------
__global__ void __launch_bounds__(256) k_p1(const int* __restrict__ grow, const int* __restrict__ gcol,
                                            int* __restrict__ bucketcur, int2* __restrict__ binned) {
    __shared__ int h1[NBKT], base1[NBKT];
    int tid = threadIdx.x;
    for (int i = tid; i < NBKT; i += 256) h1[i] = 0;
    __syncthreads();
    int idx0 = blockIdx.x * 4096;
    int r[16], c[16];
    #pragma unroll
    for (int k = 0; k < 16; ++k) {
        int i = idx0 + k * 256 + tid;
        if (i < E2) {
            r[k] = grow[i]; c[k] = gcol[i];
            atomicAdd(&h1[bucket_of(r[k])], 1);
        } else r[k] = -1;
    }
    __syncthreads();
    for (int i = tid; i < NBKT; i += 256) {
        base1[i] = h1[i] ? atomicAdd(&bucketcur[i], h1[i]) : 0;
        h1[i] = 0;
    }
    __syncthreads();
    #pragma unroll
    for (int k = 0; k < 16; ++k) {
        if (r[k] >= 0) {
            int b = bucket_of(r[k]);
            int p = base1[b] + atomicAdd(&h1[b], 1);
            binned[p] = make_int2(r[k], c[k]);
        }
    }
}

// ---------------- P2: per-bucket sort + packed (start,end) + factors -------
__global__ void __launch_bounds__(256) k_p2(const int2* __restrict__ binned, const int* __restrict__ bb,
                                            int* __restrict__ cols, int2* __restrict__ moffs,
                                            float* __restrict__ dinv, float* __restrict__ dsq,
                                            float* __restrict__ gsc) {
    __shared__ int h[1024];
    __shared__ int ws2[256];
    int b = blockIdx.x, tid = threadIdx.x;
    int r0, r1;
    if (b < 147) { r0 = b << 10; r1 = min((b + 1) << 10, N_USER); }
    else         { r0 = N_USER + ((b - 147) << 8); r1 = min(N_USER + ((b - 146) << 8), N_NODES); }
    int s0 = bb[b], e0 = bb[b + 1];
    for (int i = tid; i < 1024; i += 256) h[i] = 0;
    __syncthreads();
    for (int j = s0 + tid; j < e0; j += 256) atomicAdd(&h[binned[j].x - r0], 1);
    __syncthreads();
    int t0 = tid * 4;
    int a0 = h[t0], a1 = h[t0 + 1], a2 = h[t0 + 2], a3 = h[t0 + 3];
    ws2[tid] = a0 + a1 + a2 + a3;
    __syncthreads();
    for (int off = 1; off < 256; off <<= 1) {
        int v = (tid >= off) ? ws2[tid - off] : 0;
        __syncthreads();
        ws2[tid] += v;
        __syncthreads();
    }
    int excl = tid ? ws2[tid - 1] : 0;
    int ex[4] = { excl, excl + a0, excl + a0 + a1, excl + a0 + a1 + a2 };
    int ac[4] = { a0, a1, a2, a3 };
    #pragma unroll
    for (int i = 0; i < 4; ++i) {
        int row = r0 + t0 + i;
        if (row < r1) {
            moffs[row] = make_int2(s0 + ex[i], s0 + ex[i] + ac[i]);
            float deg = (float)ac[i];
            bool nz = deg > 0.f;
            dinv[row] = nz ? rsqrtf(deg) : 0.f;
            dsq[row]  = nz ? 1.f / deg  : 0.f;
            gsc[row]  = nz ? sqrtf(deg) : 0.f;
        }
        h[t0 + i] = ex[i];
    }
    __syncthreads();
    for (int j = s0 + tid; j < e0; j += 256) {
        int2 e = binned[j];
        int p = s0 + atomicAdd(&h[e.x - r0], 1);
        cols[p] = e.y << 7;           // byte offset into a 64-half row
    }
}

// ---------------- mhgemm device body (shared by fused launch) --------------
__device__ void mhgemm_body(int blk, const int* __restrict__ aux,
                            const unsigned short* __restrict__ WtG,
                            const unsigned short* __restrict__ WtD,
                            const unsigned short* __restrict__ WtA,
                            float* __restrict__ Xmh, float* __restrict__ cntf) {
    int seg, rb, k0, klen, Kseg, auxoff;
    const unsigned short* Wt;
    if (blk < 16)      { seg = 0; rb = blk;                      k0 = 0;              klen = 25;                  Kseg = 25;   auxoff = 1;    Wt = WtG; }
    else if (blk < 96) { int t = blk - 16; seg = 1; rb = t & 15; k0 = (t >> 4) * 512; klen = min(512, 2186 - k0); Kseg = 2186; auxoff = 26;   Wt = WtD; }
    else               { int t = blk - 96; seg = 2; rb = t & 15; k0 = (t >> 4) * 512; klen = min(512, 8030 - k0); Kseg = 8030; auxoff = 2212; Wt = WtA; }
    int lane = threadIdx.x & 63, wave = threadIdx.x >> 6;
    int m = lane & 15, quad = lane >> 4;
    int row = rb * 64 + wave * 16 + m;
    const int* arow = aux + (size_t)row * AUX_W + auxoff;

    f32x4 acc0 = {0.f,0.f,0.f,0.f}, acc1 = acc0, acc2 = acc0, acc3 = acc0;
    float asum = 0.f;
    int nchunk = (klen + 31) >> 5;
    for (int kci = 0; kci < nchunk; ++kci) {
        int kb = k0 + kci * 32 + quad * 8;
        short8 af;
        if (kb + 8 <= Kseg) {
            #pragma unroll
            for (int j = 0; j < 8; ++j) {
                int x = arow[kb + j];
                af[j] = x ? (short)0x3F80 : (short)0;
                asum += (float)x;
            }
        } else {
            #pragma unroll
            for (int j = 0; j < 8; ++j) {
                int x = (kb + j < Kseg) ? arow[kb + j] : 0;
                af[j] = x ? (short)0x3F80 : (short)0;
                asum += (float)x;
            }
        }
        size_t kcg = (size_t)(k0 >> 5) + kci;
        const unsigned short* bp = Wt + ((kcg * 64 + m) * 4 + quad) * 8;
        short8 b0 = *(const short8*)(bp);
        short8 b1 = *(const short8*)(bp + 512);
        short8 b2 = *(const short8*)(bp + 1024);
        short8 b3 = *(const short8*)(bp + 1536);
        acc0 = __builtin_amdgcn_mfma_f32_16x16x32_bf16(af, b0, acc0, 0, 0, 0);
        acc1 = __builtin_amdgcn_mfma_f32_16x16x32_bf16(af, b1, acc1, 0, 0, 0);
        acc2 = __builtin_amdgcn_mfma_f32_16x16x32_bf16(af, b2, acc2, 0, 0, 0);
        acc3 = __builtin_amdgcn_mfma_f32_16x16x32_bf16(af, b3, acc3, 0, 0, 0);
    }
    asum += __shfl_xor(asum, 16);
    asum += __shfl_xor(asum, 32);
    if (quad == 0) atomicAdd(&cntf[seg * BATCH + row], asum);
    float* xbase = Xmh + ((size_t)seg * BATCH + rb * 64 + wave * 16 + quad * 4) * 64;
    #pragma unroll
    for (int reg = 0; reg < 4; ++reg) {
        float* xr = xbase + (size_t)reg * 64;
        atomicAdd(&xr[ 0 + m], acc0[reg]);
        atomicAdd(&xr[16 + m], acc1[reg]);
        atomicAdd(&xr[32 + m], acc2[reg]);
        atomicAdd(&xr[48 + m], acc3[reg]);
    }
}

// ---------------- fused: mhgemm + mark + tacc0 + emb cvt -------------------
// LONG-POLE FIRST block order: [0,352) mhgemm; [352,864) mark; [864,1376)
// tacc0; [1376,1376+cvtN) cvt.
__global__ void __launch_bounds__(256) k_cvt_fused(const void* rawU, const void* rawI,
                                                   const float* __restrict__ dinv,
                                                   __half* __restrict__ emb,
                                                   float* __restrict__ tacc,
                                                   const int* __restrict__ uids,
                                                   const int* __restrict__ iids, int cvtN,
                                                   const int2* __restrict__ moffs,
                                                   const int* __restrict__ cols,
                                                   int2* __restrict__ moffs2,
                                                   const int* __restrict__ aux,
                                                   const unsigned short* __restrict__ WtG,
                                                   const unsigned short* __restrict__ WtD,
                                                   const unsigned short* __restrict__ WtA,
                                                   float* __restrict__ Xmh, float* __restrict__ cntf) {
    int blk = blockIdx.x;
    if (blk < 352) {                          // mhgemm (long pole, starts first)
        mhgemm_body(blk, aux, WtG, WtD, WtA, Xmh, cntf);
        return;
    }
    if (blk < 864) {                          // mark: moffs2[r] for T u N(T)
        int lane = threadIdx.x & 63;
        int t = (blk - 352) * 4 + (threadIdx.x >> 6);
        int r = (t < BATCH) ? uids[t] : (N_USER + iids[t - BATCH]);
        int2 se = moffs[r];
        if (lane == 0) moffs2[r] = se;
        for (int j = se.x + lane; j < se.y; j += 64) {
            int c = (unsigned)cols[j] >> 7;
            moffs2[c] = moffs[c];             // benign dup races: same value
        }
        return;
    }
    int isf32 = detect_f32(rawU);
    if (blk < 1376) {                         // tacc0: init from RAW rows
        int lane = threadIdx.x & 63;
        int t = (blk - 864) * 4 + (threadIdx.x >> 6);
        const void* src; size_t ri;
        if (t < BATCH) { src = rawU; ri = (size_t)uids[t]; }
        else           { src = rawI; ri = (size_t)iids[t - BATCH]; }
        float v;
        if (isf32) v = ((const float*)src)[ri * 64 + lane];
        else       v = __bfloat162float(((const __hip_bfloat16*)src)[ri * 64 + lane]);
        tacc[(size_t)t * 64 + lane] = v;
        return;
    }
    int q = (blk - 1376) * 256 + threadIdx.x; // quad index (4 elems)
    if (q >= N_NODES * 16) return;
    int r = q >> 4;
    const void* src; size_t qq;
    if (r < N_USER) { src = rawU; qq = (size_t)q; }
    else            { src = rawI; qq = (size_t)q - (size_t)N_USER * 16; }
    float d = dinv[r];
    float4 v;
    if (isf32) {
        v = ((const float4*)src)[qq];
    } else {
        ushort4 u = ((const ushort4*)src)[qq];
        v.x = __bfloat162float(*(__hip_bfloat16*)&u.x);
        v.y = __bfloat162float(*(__hip_bfloat16*)&u.y);
        v.z = __bfloat162float(*(__hip_bfloat16*)&u.z);
        v.w = __bfloat162float(*(__hip_bfloat16*)&u.w);
    }
    __half h0 = __float2half(v.x * d), h1 = __float2half(v.y * d);
    __half h2 = __float2half(v.z * d), h3 = __float2half(v.w * d);
    ushort4 o = { *(unsigned short*)&h0, *(unsigned short*)&h1,
                  *(unsigned short*)&h2, *(unsigned short*)&h3 };
    ((ushort4*)emb)[(size_t)q] = o;
}

// ---------------- SpMV inner helpers: N-slot edge blocks -------------------
// lane = (p,ep): p feature-pair in [0,32), ep edge parity. One gather = 2 edges.
// unclamped N-slot block (N/2 gathers), requires j0+N <= e.
#define SPMV_BLOCK(N)                                                          \
    {                                                                          \
        int c[(N)/2];                                                          \
        _Pragma("unroll")                                                      \
        for (int u = 0; u < (N)/2; ++u) c[u] = cols[j0 + 2*u + ep];            \
        float2 v[(N)/2];                                                       \
        _Pragma("unroll")                                                      \
        for (int u = 0; u < (N)/2; ++u)                                        \
            v[u] = __half22float2(*(const __half2*)(sb + (size_t)(unsigned)c[u])); \
        _Pragma("unroll")                                                      \
        for (int u = 0; u < (N)/2; ++u) { ax += v[u].x; ay += v[u].y; }        \
    }

// clamped 4-slot block for the <4 remainder
#define SPMV_TAIL4()                                                           \
    {                                                                          \
        int c[2]; float w[2];                                                  \
        _Pragma("unroll")                                                      \
        for (int u = 0; u < 2; ++u) {                                          \
            int j = j0 + 2*u + ep;                                             \
            c[u] = cols[min(j, e - 1)];                                        \
            w[u] = (j < e) ? 1.f : 0.f;                                        \
        }                                                                      \
        float2 v[2];                                                           \
        _Pragma("unroll")                                                      \
        for (int u = 0; u < 2; ++u)                                            \
            v[u] = __half22float2(*(const __half2*)(sb + (size_t)(unsigned)c[u])); \
        _Pragma("unroll")                                                      \
        for (int u = 0; u < 2; ++u) { ax = fmaf(w[u], v[u].x, ax); ay = fmaf(w[u], v[u].y, ay); } \
    }

// ---------------- f-domain SpMV, half2 layout, hierarchical tail -----------
// Appended blocks [spmvN, spmvN+512): tacc += g[r]*src[r] (reads INPUT buf).
__global__ void __launch_bounds__(256, 8) k_spmv(const __half* __restrict__ src, __half* __restrict__ dst,
                                                 const int2* __restrict__ moffs_in, const int* __restrict__ cols,
                                                 const float* __restrict__ dsq,
                                                 int spmvN, float* __restrict__ tacc,
                                                 const int* __restrict__ uids, const int* __restrict__ iids,
                                                 const float* __restrict__ gsc) {
    int tid = threadIdx.x, lane = tid & 63;
    int blk = blockIdx.x;
    if (blk >= spmvN) {                       // fused tacc layer update
        int t = (blk - spmvN) * 4 + (tid >> 6);
        int r = (t < BATCH) ? uids[t] : (N_USER + iids[t - BATCH]);
        tacc[(size_t)t * 64 + lane] += __half2float(src[(size_t)r * 64 + lane]) * gsc[r];
        return;
    }
    int wid = blk * 4 + (tid >> 6);
    if (wid >= N_NODES) return;
    int2 se = moffs_in[wid];
    int s = se.x, e = se.y;
    if (e <= s) return;
    int p = lane & 31, ep = lane >> 5;
    const char* sb = (const char*)src + (p << 2);
    float ax = 0.f, ay = 0.f;
    int j0 = s;
    for (; j0 + 16 <= e; j0 += 16) SPMV_BLOCK(16)
    if (j0 + 8 <= e) { SPMV_BLOCK(8) j0 += 8; }
    if (j0 + 4 <= e) { SPMV_BLOCK(4) j0 += 4; }
    if (j0 < e) SPMV_TAIL4()
    ax += __shfl_xor(ax, 32);
    ay += __shfl_xor(ay, 32);
    if (ep == 0) {
        float d = dsq[wid];
        *(__half2*)((char*)dst + ((size_t)wid << 7) + (p << 2)) = __floats2half2_rn(ax * d, ay * d);
    }
}

// ---------------- layer-3 SpMV fused into tacc + self term -----------------
__global__ void __launch_bounds__(256) k_spmv3(const __half* __restrict__ src, float* __restrict__ tacc,
                                               const int2* __restrict__ moffs, const int* __restrict__ cols,
                                               const float* __restrict__ dinv, const float* __restrict__ gsc,
                                               const int* __restrict__ uids, const int* __restrict__ iids) {
    int tid = threadIdx.x, lane = tid & 63;
    int t = blockIdx.x * 4 + (tid >> 6);
    if (t >= 2048) return;
    int r = (t < BATCH) ? uids[t] : (N_USER + iids[t - BATCH]);
    int2 se = moffs[r];
    int s = se.x, e = se.y;
    int p = lane & 31, ep = lane >> 5;
    const char* sb = (const char*)src + (p << 2);
    float ax = 0.f, ay = 0.f;
    int j0 = s;
    if (e > s) {
        for (; j0 + 16 <= e; j0 += 16) SPMV_BLOCK(16)
        if (j0 + 8 <= e) { SPMV_BLOCK(8) j0 += 8; }
        if (j0 + 4 <= e) { SPMV_BLOCK(4) j0 += 4; }
        if (j0 < e) SPMV_TAIL4()
    }
    ax += __shfl_xor(ax, 32);
    ay += __shfl_xor(ay, 32);
    if (ep == 0) {
        float2 self = __half22float2(*(const __half2*)((const char*)src + ((size_t)r << 7) + (p << 2)));
        float di = dinv[r], g = gsc[r];
        float* tp = tacc + (size_t)t * 64 + (p << 1);
        tp[0] += di * ax + g * self.x;
        tp[1] += di * ay + g * self.y;
    }
}

// ---------------- fused X-assembly + MLP -----------------------------------
__global__ void __launch_bounds__(256) k_mlp(const int* __restrict__ aux,
                                             const float* __restrict__ ratef, const float* __restrict__ genderf,
                                             const float* __restrict__ agef, const float* __restrict__ occf,
                                             const float* __restrict__ areaf, const float* __restrict__ tacc,
                                             const float* __restrict__ Xmh, const float* __restrict__ cntf,
                                             const float* __restrict__ W1, const float* __restrict__ b1,
                                             const float* __restrict__ W2, const float* __restrict__ b2,
                                             const float* __restrict__ Wo, const float* __restrict__ bo,
                                             void* __restrict__ out, const void* probe) {
    __shared__ float sx[4][640];
    __shared__ float sh[4][64];
    int isf32 = detect_f32(probe);
    int lane = threadIdx.x & 63, w = threadIdx.x >> 6;
    int b = blockIdx.x * 4 + w;
    const int* arow = aux + (size_t)b * AUX_W;
    float* xr = sx[w];
    xr[0   + lane] = ratef[arow[0] * 64 + lane];
    xr[64  + lane] = Xmh[((size_t)0 * BATCH + b) * 64 + lane] / cntf[0 * BATCH + b];
    xr[128 + lane] = Xmh[((size_t)1 * BATCH + b) * 64 + lane] / cntf[1 * BATCH + b];
    xr[192 + lane] = Xmh[((size_t)2 * BATCH + b) * 64 + lane] / cntf[2 * BATCH + b];
    xr[256 + lane] = genderf[arow[10242] * 64 + lane];
    xr[320 + lane] = agef[arow[10243] * 64 + lane];
    xr[384 + lane] = occf[arow[10244] * 64 + lane];
    xr[448 + lane] = areaf[arow[10245] * 64 + lane];
    xr[512 + lane] = tacc[(size_t)b * 64 + lane] * 0.25f;
    xr[576 + lane] = tacc[(size_t)(BATCH + b) * 64 + lane] * 0.25f;
    float acc = b1[lane];
    #pragma unroll 8
    for (int k = 0; k < 640; ++k) acc += xr[k] * W1[(size_t)k * 64 + lane];
    float h1 = fmaxf(acc, 0.f);
    sh[w][lane] = h1;
    float acc2 = b2[lane];
    #pragma unroll 8
    for (int j = 0; j < 64; ++j) acc2 += sh[w][j] * W2[(size_t)j * 64 + lane];
    float h2 = fmaxf(acc2, 0.f);
    float p = h2 * Wo[lane];
    #pragma unroll
    for (int off = 32; off; off >>= 1) p += __shfl_down(p, off);
    if (lane == 0) {
        float r = p + bo[0];
        if (isf32) ((float*)out)[b] = r;
        else       ((__hip_bfloat16*)out)[b] = __float2bfloat16(r);
    }
}

extern "C" void kernel_launch(void* const* d_in, const int* in_sizes, int n_in,
                              void* d_out, int out_size, void* d_ws, size_t ws_size,
                              hipStream_t stream) {
    const int* aux  = (const int*)d_in[0];
    const int* uids = (const int*)d_in[1];
    const int* iids = (const int*)d_in[2];
    const int* grow = (const int*)d_in[3];
    const int* gcol = (const int*)d_in[4];

    char* p = (char*)d_ws;
    auto alloc = [&](size_t bytes) -> char* {
        char* r = p;
        p += (bytes + 255) / 256 * 256;
        return r;
    };
    // zero-region (one hipMemsetAsync): bucket_tot, Xmh, cntf, moffs2
    int*   bucket_tot  = (int*)alloc(512 * 4);
    float* Xmh         = (float*)alloc((size_t)3 * BATCH * 64 * 4);
    float* cntf        = (float*)alloc((size_t)3 * BATCH * 4);
    int2*  moffs2      = (int2*)alloc((size_t)180224 * 8);
    char*  zero_end    = p;
    int*   bucket_base = (int*)alloc(512 * 4);
    int*   bucketcur   = (int*)alloc(512 * 4);
    int2*  moffs       = (int2*)alloc((size_t)180224 * 8);
    float* dinv        = (float*)alloc((size_t)180224 * 4);
    float* dsq         = (float*)alloc((size_t)180224 * 4);
    float* gsc         = (float*)alloc((size_t)180224 * 4);
    int2*  binned      = (int2*)alloc((size_t)E2 * 8);
    int*   cols        = (int*)alloc((size_t)E2 * 4);
    __half* embA       = (__half*)alloc((size_t)N_NODES * 64 * 2);
    __half* embB       = (__half*)alloc((size_t)N_NODES * 64 * 2);
    float* tacc        = (float*)alloc((size_t)2048 * 64 * 4);
    unsigned short* WtG = (unsigned short*)alloc((size_t)KP_G * 64 * 2);
    unsigned short* WtD = (unsigned short*)alloc((size_t)KP_D * 64 * 2);
    unsigned short* WtA = (unsigned short*)alloc((size_t)KP_A * 64 * 2);
    float* ratef   = (float*)alloc(384 * 4);
    float* genderf = (float*)alloc(128 * 4);
    float* agef    = (float*)alloc(448 * 4);
    float* occf    = (float*)alloc(1344 * 4);
    float* areaf   = (float*)alloc((size_t)217728 * 4);
    float* fc1W    = (float*)alloc((size_t)40960 * 4);
    float* fc1b    = (float*)alloc(64 * 4);
    float* fc2W    = (float*)alloc(4096 * 4);
    float* fc2b    = (float*)alloc(64 * 4);
    float* outW    = (float*)alloc(64 * 4);
    float* outb    = (float*)alloc(4);

    const void* probe = d_in[14];   // user_rel, for inline dtype detect

    // 0. zero accumulators (single contiguous region, DMA)
    hipMemsetAsync(bucket_tot, 0, (size_t)(zero_end - (char*)bucket_tot), stream);

    // 1. fused prep: table cvt + Wt pack + bucket counts
    CvtBatch cb;
    int blk = 0, si = 0;
    auto addseg = [&](const void* s, float* d, int n) {
        cb.seg[si].src = s; cb.seg[si].dst = d; cb.seg[si].n = n; cb.seg[si].blk0 = blk;
        blk += (n + 255) / 256; ++si;
    };
    addseg(d_in[6],  ratef,   384);
    addseg(d_in[10], genderf, 128);
    addseg(d_in[11], agef,    448);
    addseg(d_in[12], occf,    1344);
    addseg(d_in[13], areaf,   217728);
    addseg(d_in[16], fc1W,   40960);
    addseg(d_in[17], fc1b,   64);
    addseg(d_in[18], fc2W,   4096);
    addseg(d_in[19], fc2b,   64);
    addseg(d_in[20], outW,   64);
    addseg(d_in[21], outb,   1);
    for (int i = si; i < 16; ++i) { cb.seg[i].src = nullptr; cb.seg[i].dst = nullptr; cb.seg[i].n = 0; cb.seg[i].blk0 = 0x7fffffff; }
    const int cvtBlks = blk;
    hipLaunchKernelGGL(k_prep, dim3(cvtBlks + WT_BLKS + BCNT_BLKS), dim3(256), 0, stream,
                       cb, cvtBlks, d_in[7], d_in[8], d_in[9], WtG, WtD, WtA, grow, bucket_tot, probe);

    // 2. CSR build
    hipLaunchKernelGGL(k_bscan, dim3(1), dim3(512), 0, stream, bucket_tot, bucket_base, bucketcur);
    hipLaunchKernelGGL(k_p1, dim3((E2 + 4095) / 4096), dim3(256), 0, stream, grow, gcol, bucketcur, binned);
    hipLaunchKernelGGL(k_p2, dim3(NBKT), dim3(256), 0, stream, binned, bucket_base, cols, moffs, dinv, dsq, gsc);

    // 3. fused (long-pole-first): mhgemm + mark + tacc0 + emb cvt
    const int cvtN = (N_NODES * 16 + 255) / 256;
    hipLaunchKernelGGL(k_cvt_fused, dim3(1376 + cvtN), dim3(256), 0, stream,
                       d_in[14], d_in[15], dinv, embA, tacc, uids, iids, cvtN,
                       moffs, cols, moffs2, aux, WtG, WtD, WtA, Xmh, cntf);

    // 4. LightGCN: L1 unmasked; L2 via moffs2 (+fused tacc f1); L3 at T (+self)
    const int spmvN = (N_NODES + 3) / 4;
    hipLaunchKernelGGL(k_spmv, dim3(spmvN), dim3(256), 0, stream,
                       embA, embB, moffs, cols, dsq, spmvN, (float*)nullptr, uids, iids, gsc);
    hipLaunchKernelGGL(k_spmv, dim3(spmvN + 512), dim3(256), 0, stream,
                       embB, embA, moffs2, cols, dsq, spmvN, tacc, uids, iids, gsc);
    hipLaunchKernelGGL(k_spmv3, dim3(2048 / 4), dim3(256), 0, stream,
                       embA, tacc, moffs, cols, dinv, gsc, uids, iids);

    // 5. fused X+MLP -> out
    hipLaunchKernelGGL(k_mlp, dim3(BATCH / 4), dim3(256), 0, stream,
                       aux, ratef, genderf, agef, occf, areaf, tacc, Xmh, cntf,
                       fc1W, fc1b, fc2W, fc2b, outW, outb, d_out, probe);
}

// Round 13
// 335.233 us; speedup vs baseline: 1.0059x; 1.0059x over previous
//
#include <hip/hip_runtime.h>
#include <hip/hip_bf16.h>
#include <hip/hip_fp16.h>

#define N_USER 150000
#define M_ITEM 30000
#define N_NODES 180000
#define E2 1200000
#define BATCH 1024
#define AUX_W 10246
#define KP_G 32
#define KP_D 2208
#define KP_A 8064
#define NBKT 265       // 147 user buckets (1024 rows) + 118 item buckets (256 rows)
#define WT_BLKS 2576   // ((KP_G+KP_D+KP_A)*64 + 255)/256
#define BCNT_BLKS 293  // (E2 + 4095)/4096

typedef __attribute__((ext_vector_type(8))) short short8;
typedef __attribute__((ext_vector_type(4))) float f32x4;

__device__ __forceinline__ int bucket_of(int r) {
    return r < N_USER ? (r >> 10) : 147 + ((r - N_USER) >> 8);
}

// inline dtype detect (wave-uniform): bf16 data reads small; f32-as-bf16 huge.
__device__ __forceinline__ int detect_f32(const void* probe) {
    float v = __bfloat162float(((const __hip_bfloat16*)probe)[threadIdx.x & 63]);
    unsigned long long m = __ballot(!(fabsf(v) < 1000.0f));
    return __popcll(m) > 8;
}

// ---------------- fused prep: table cvt + Wt pack + bucket counts ----------
struct CvtSeg { const void* src; float* dst; int n; int blk0; };
struct CvtBatch { CvtSeg seg[16]; };

__global__ void __launch_bounds__(256) k_prep(CvtBatch cb, int cvtBlks,
                                              const void* Wg, const void* Wd, const void* Wa,
                                              unsigned short* WtG, unsigned short* WtD, unsigned short* WtA,
                                              const int* __restrict__ grow, int* __restrict__ bucket_tot,
                                              const void* probe) {
    int blk = blockIdx.x, tid = threadIdx.x;
    if (blk < cvtBlks) {                       // --- small-table f32 conversion
        int isf32 = detect_f32(probe);
        int si = 0;
        #pragma unroll
        for (int i = 0; i < 16; ++i) if (blk >= cb.seg[i].blk0) si = i;
        const CvtSeg sg = cb.seg[si];
        int i = (blk - sg.blk0) * 256 + tid;
        if (i >= sg.n) return;
        if (isf32) sg.dst[i] = ((const float*)sg.src)[i];
        else       sg.dst[i] = __bfloat162float(((const __hip_bfloat16*)sg.src)[i]);
        return;
    }
    if (blk < cvtBlks + WT_BLKS) {             // --- Wt B-fragment pack
        int isf32 = detect_f32(probe);
        int t = (blk - cvtBlks) * 256 + tid;
        if (t >= (KP_G + KP_D + KP_A) * 64) return;
        int kp = t >> 6, n = t & 63;
        int k, K; const void* src; unsigned short* dst;
        if (kp < KP_G)              { k = kp;               K = 25;   src = Wg; dst = WtG; }
        else if (kp < KP_G + KP_D)  { k = kp - KP_G;        K = 2186; src = Wd; dst = WtD; }
        else                        { k = kp - KP_G - KP_D; K = 8030; src = Wa; dst = WtA; }
        unsigned short v = 0;
        if (k < K) {
            if (isf32) {
                __hip_bfloat16 h = __float2bfloat16(((const float*)src)[(size_t)k * 64 + n]);
                v = *(unsigned short*)&h;
            } else {
                v = ((const unsigned short*)src)[(size_t)k * 64 + n];
            }
        }
        dst[(((size_t)(k >> 5) * 64 + n) * 4 + ((k >> 3) & 3)) * 8 + (k & 7)] = v;
        return;
    }
    // --- bucket counts (bucket_tot pre-zeroed by memset before this launch)
    __shared__ int h[NBKT];
    for (int i = tid; i < NBKT; i += 256) h[i] = 0;
    __syncthreads();
    int idx0 = (blk - cvtBlks - WT_BLKS) * 4096;
    #pragma unroll
    for (int k = 0; k < 16; ++k) {
        int i = idx0 + k * 256 + tid;
        if (i < E2) atomicAdd(&h[bucket_of(grow[i])], 1);
    }
    __syncthreads();
    for (int i = tid; i < NBKT; i += 256) if (h[i]) atomicAdd(&bucket_tot[i], h[i]);
}

// ---------------- bucket scan ----------------
__global__ void __launch_bounds__(512) k_bscan(const int* __restrict__ bucket_tot,
                                               int* __restrict__ bucket_base,
                                               int* __restrict__ bucketcur) {
    __shared__ int s[512];
    int tid = threadIdx.x;
    s[tid] = (tid < NBKT) ? bucket_tot[tid] : 0;
    __syncthreads();
    for (int off = 1; off < 512; off <<= 1) {
        int v = (tid >= off) ? s[tid - off] : 0;
        __syncthreads();
        s[tid] += v;
        __syncthreads();
    }
    int excl = tid ? s[tid - 1] : 0;
    bucket_base[tid] = excl;                 // bucket_base[NBKT] = E2
    if (tid < NBKT) bucketcur[tid] = excl;
}

// ---------------- P1: bin edges into NBKT row-range buckets ----------------
__global__ void __launch_bounds__(256) k_p1(const int* __restrict__ grow, const int* __restrict__ gcol,
                                            int* __restrict__ bucketcur, int2* __restrict__ binned) {
    __shared__ int h1[NBKT], base1[NBKT];
    int tid = threadIdx.x;
    for (int i = tid; i < NBKT; i += 256) h1[i] = 0;
    __syncthreads();
    int idx0 = blockIdx.x * 4096;
    int r[16], c[16];
    #pragma unroll
    for (int k = 0; k < 16; ++k) {
        int i = idx0 + k * 256 + tid;
        if (i < E2) {
            r[k] = grow[i]; c[k] = gcol[i];
            atomicAdd(&h1[bucket_of(r[k])], 1);
        } else r[k] = -1;
    }
    __syncthreads();
    for (int i = tid; i < NBKT; i += 256) {
        base1[i] = h1[i] ? atomicAdd(&bucketcur[i], h1[i]) : 0;
        h1[i] = 0;
    }
    __syncthreads();
    #pragma unroll
    for (int k = 0; k < 16; ++k) {
        if (r[k] >= 0) {
            int b = bucket_of(r[k]);
            int p = base1[b] + atomicAdd(&h1[b], 1);
            binned[p] = make_int2(r[k], c[k]);
        }
    }
}

// ---------------- P2: per-bucket sort + packed (start,end) + factors -------
__global__ void __launch_bounds__(256) k_p2(const int2* __restrict__ binned, const int* __restrict__ bb,
                                            int* __restrict__ cols, int2* __restrict__ moffs,
                                            float* __restrict__ dinv, float* __restrict__ dsq,
                                            float* __restrict__ gsc) {
    __shared__ int h[1024];
    __shared__ int ws2[256];
    int b = blockIdx.x, tid = threadIdx.x;
    int r0, r1;
    if (b < 147) { r0 = b << 10; r1 = min((b + 1) << 10, N_USER); }
    else         { r0 = N_USER + ((b - 147) << 8); r1 = min(N_USER + ((b - 146) << 8), N_NODES); }
    int s0 = bb[b], e0 = bb[b + 1];
    for (int i = tid; i < 1024; i += 256) h[i] = 0;
    __syncthreads();
    for (int j = s0 + tid; j < e0; j += 256) atomicAdd(&h[binned[j].x - r0], 1);
    __syncthreads();
    int t0 = tid * 4;
    int a0 = h[t0], a1 = h[t0 + 1], a2 = h[t0 + 2], a3 = h[t0 + 3];
    ws2[tid] = a0 + a1 + a2 + a3;
    __syncthreads();
    for (int off = 1; off < 256; off <<= 1) {
        int v = (tid >= off) ? ws2[tid - off] : 0;
        __syncthreads();
        ws2[tid] += v;
        __syncthreads();
    }
    int excl = tid ? ws2[tid - 1] : 0;
    int ex[4] = { excl, excl + a0, excl + a0 + a1, excl + a0 + a1 + a2 };
    int ac[4] = { a0, a1, a2, a3 };
    #pragma unroll
    for (int i = 0; i < 4; ++i) {
        int row = r0 + t0 + i;
        if (row < r1) {
            moffs[row] = make_int2(s0 + ex[i], s0 + ex[i] + ac[i]);
            float deg = (float)ac[i];
            bool nz = deg > 0.f;
            dinv[row] = nz ? rsqrtf(deg) : 0.f;
            dsq[row]  = nz ? 1.f / deg  : 0.f;
            gsc[row]  = nz ? sqrtf(deg) : 0.f;
        }
        h[t0 + i] = ex[i];
    }
    __syncthreads();
    for (int j = s0 + tid; j < e0; j += 256) {
        int2 e = binned[j];
        int p = s0 + atomicAdd(&h[e.x - r0], 1);
        cols[p] = e.y << 7;           // byte offset into a 64-half row
    }
}

// ---------------- mhgemm device body (shared by fused launch) --------------
__device__ void mhgemm_body(int blk, const int* __restrict__ aux,
                            const unsigned short* __restrict__ WtG,
                            const unsigned short* __restrict__ WtD,
                            const unsigned short* __restrict__ WtA,
                            float* __restrict__ Xmh, float* __restrict__ cntf) {
    int seg, rb, k0, klen, Kseg, auxoff;
    const unsigned short* Wt;
    if (blk < 16)      { seg = 0; rb = blk;                      k0 = 0;              klen = 25;                  Kseg = 25;   auxoff = 1;    Wt = WtG; }
    else if (blk < 96) { int t = blk - 16; seg = 1; rb = t & 15; k0 = (t >> 4) * 512; klen = min(512, 2186 - k0); Kseg = 2186; auxoff = 26;   Wt = WtD; }
    else               { int t = blk - 96; seg = 2; rb = t & 15; k0 = (t >> 4) * 512; klen = min(512, 8030 - k0); Kseg = 8030; auxoff = 2212; Wt = WtA; }
    int lane = threadIdx.x & 63, wave = threadIdx.x >> 6;
    int m = lane & 15, quad = lane >> 4;
    int row = rb * 64 + wave * 16 + m;
    const int* arow = aux + (size_t)row * AUX_W + auxoff;

    f32x4 acc0 = {0.f,0.f,0.f,0.f}, acc1 = acc0, acc2 = acc0, acc3 = acc0;
    float asum = 0.f;
    int nchunk = (klen + 31) >> 5;
    for (int kci = 0; kci < nchunk; ++kci) {
        int kb = k0 + kci * 32 + quad * 8;
        short8 af;
        if (kb + 8 <= Kseg) {
            #pragma unroll
            for (int j = 0; j < 8; ++j) {
                int x = arow[kb + j];
                af[j] = x ? (short)0x3F80 : (short)0;
                asum += (float)x;
            }
        } else {
            #pragma unroll
            for (int j = 0; j < 8; ++j) {
                int x = (kb + j < Kseg) ? arow[kb + j] : 0;
                af[j] = x ? (short)0x3F80 : (short)0;
                asum += (float)x;
            }
        }
        size_t kcg = (size_t)(k0 >> 5) + kci;
        const unsigned short* bp = Wt + ((kcg * 64 + m) * 4 + quad) * 8;
        short8 b0 = *(const short8*)(bp);
        short8 b1 = *(const short8*)(bp + 512);
        short8 b2 = *(const short8*)(bp + 1024);
        short8 b3 = *(const short8*)(bp + 1536);
        acc0 = __builtin_amdgcn_mfma_f32_16x16x32_bf16(af, b0, acc0, 0, 0, 0);
        acc1 = __builtin_amdgcn_mfma_f32_16x16x32_bf16(af, b1, acc1, 0, 0, 0);
        acc2 = __builtin_amdgcn_mfma_f32_16x16x32_bf16(af, b2, acc2, 0, 0, 0);
        acc3 = __builtin_amdgcn_mfma_f32_16x16x32_bf16(af, b3, acc3, 0, 0, 0);
    }
    asum += __shfl_xor(asum, 16);
    asum += __shfl_xor(asum, 32);
    if (quad == 0) atomicAdd(&cntf[seg * BATCH + row], asum);
    float* xbase = Xmh + ((size_t)seg * BATCH + rb * 64 + wave * 16 + quad * 4) * 64;
    #pragma unroll
    for (int reg = 0; reg < 4; ++reg) {
        float* xr = xbase + (size_t)reg * 64;
        atomicAdd(&xr[ 0 + m], acc0[reg]);
        atomicAdd(&xr[16 + m], acc1[reg]);
        atomicAdd(&xr[32 + m], acc2[reg]);
        atomicAdd(&xr[48 + m], acc3[reg]);
    }
}

// ---------------- fused: mhgemm + mark + tacc0 + emb cvt -------------------
// LONG-POLE FIRST block order: [0,352) mhgemm; [352,864) mark; [864,1376)
// tacc0; [1376,1376+cvtN) cvt.
__global__ void __launch_bounds__(256) k_cvt_fused(const void* rawU, const void* rawI,
                                                   const float* __restrict__ dinv,
                                                   __half* __restrict__ emb,
                                                   float* __restrict__ tacc,
                                                   const int* __restrict__ uids,
                                                   const int* __restrict__ iids, int cvtN,
                                                   const int2* __restrict__ moffs,
                                                   const int* __restrict__ cols,
                                                   int2* __restrict__ moffs2,
                                                   const int* __restrict__ aux,
                                                   const unsigned short* __restrict__ WtG,
                                                   const unsigned short* __restrict__ WtD,
                                                   const unsigned short* __restrict__ WtA,
                                                   float* __restrict__ Xmh, float* __restrict__ cntf) {
    int blk = blockIdx.x;
    if (blk < 352) {                          // mhgemm (long pole, starts first)
        mhgemm_body(blk, aux, WtG, WtD, WtA, Xmh, cntf);
        return;
    }
    if (blk < 864) {                          // mark: moffs2[r] for T u N(T)
        int lane = threadIdx.x & 63;
        int t = (blk - 352) * 4 + (threadIdx.x >> 6);
        int r = (t < BATCH) ? uids[t] : (N_USER + iids[t - BATCH]);
        int2 se = moffs[r];
        if (lane == 0) moffs2[r] = se;
        for (int j = se.x + lane; j < se.y; j += 64) {
            int c = (unsigned)cols[j] >> 7;
            moffs2[c] = moffs[c];             // benign dup races: same value
        }
        return;
    }
    int isf32 = detect_f32(rawU);
    if (blk < 1376) {                         // tacc0: init from RAW rows
        int lane = threadIdx.x & 63;
        int t = (blk - 864) * 4 + (threadIdx.x >> 6);
        const void* src; size_t ri;
        if (t < BATCH) { src = rawU; ri = (size_t)uids[t]; }
        else           { src = rawI; ri = (size_t)iids[t - BATCH]; }
        float v;
        if (isf32) v = ((const float*)src)[ri * 64 + lane];
        else       v = __bfloat162float(((const __hip_bfloat16*)src)[ri * 64 + lane]);
        tacc[(size_t)t * 64 + lane] = v;
        return;
    }
    int q = (blk - 1376) * 256 + threadIdx.x; // quad index (4 elems)
    if (q >= N_NODES * 16) return;
    int r = q >> 4;
    const void* src; size_t qq;
    if (r < N_USER) { src = rawU; qq = (size_t)q; }
    else            { src = rawI; qq = (size_t)q - (size_t)N_USER * 16; }
    float d = dinv[r];
    float4 v;
    if (isf32) {
        v = ((const float4*)src)[qq];
    } else {
        ushort4 u = ((const ushort4*)src)[qq];
        v.x = __bfloat162float(*(__hip_bfloat16*)&u.x);
        v.y = __bfloat162float(*(__hip_bfloat16*)&u.y);
        v.z = __bfloat162float(*(__hip_bfloat16*)&u.z);
        v.w = __bfloat162float(*(__hip_bfloat16*)&u.w);
    }
    __half h0 = __float2half(v.x * d), h1 = __float2half(v.y * d);
    __half h2 = __float2half(v.z * d), h3 = __float2half(v.w * d);
    ushort4 o = { *(unsigned short*)&h0, *(unsigned short*)&h1,
                  *(unsigned short*)&h2, *(unsigned short*)&h3 };
    ((ushort4*)emb)[(size_t)q] = o;
}

// ---------------- row-pair f-domain SpMV -----------------------------------
// Each WAVE handles rows (2w, 2w+1): one int4 loads both moffs; per 16-slot
// chunk the cols loads + gathers of BOTH rows issue interleaved (16
// outstanding gathers/wave). lane=(p,ep): p feature-pair, ep edge parity.
// Clamped indices stay in [0,E2); gathered garbage is real finite fp16 x w=0.
// Appended blocks [spmvN, spmvN+512): tacc += g[r]*src[r] (reads INPUT buf).
__global__ void __launch_bounds__(256, 8) k_spmv(const __half* __restrict__ src, __half* __restrict__ dst,
                                                 const int2* __restrict__ moffs_in, const int* __restrict__ cols,
                                                 const float* __restrict__ dsq,
                                                 int spmvN, float* __restrict__ tacc,
                                                 const int* __restrict__ uids, const int* __restrict__ iids,
                                                 const float* __restrict__ gsc) {
    int tid = threadIdx.x, lane = tid & 63;
    int blk = blockIdx.x;
    if (blk >= spmvN) {                       // fused tacc layer update
        int t = (blk - spmvN) * 4 + (tid >> 6);
        int r = (t < BATCH) ? uids[t] : (N_USER + iids[t - BATCH]);
        tacc[(size_t)t * 64 + lane] += __half2float(src[(size_t)r * 64 + lane]) * gsc[r];
        return;
    }
    int base = blk * 8 + (tid >> 6) * 2;      // first row of pair (even)
    if (base >= N_NODES) return;
    int4 mo = *(const int4*)&moffs_in[base];  // (s0,e0,s1,e1); 16B-aligned
    int s0 = mo.x, e0 = mo.y;
    int s1 = mo.z, e1 = mo.w;
    if (base + 1 >= N_NODES) { s1 = 0; e1 = 0; }
    int d0 = e0 - s0, d1 = e1 - s1;
    int dmax = max(d0, d1);
    if (dmax <= 0) return;
    int p = lane & 31, ep = lane >> 5;
    const char* sb = (const char*)src + (p << 2);
    float ax0 = 0.f, ay0 = 0.f, ax1 = 0.f, ay1 = 0.f;
    for (int cb = 0; cb < dmax; cb += 16) {
        int c0[8], c1[8]; float w0[8], w1[8];
        #pragma unroll
        for (int u = 0; u < 8; ++u) {
            int j = cb + 2 * u + ep;
            int j0a = s0 + j, j1a = s1 + j;
            c0[u] = cols[max(min(j0a, e0 - 1), 0)];
            w0[u] = (j0a < e0) ? 1.f : 0.f;
            c1[u] = cols[max(min(j1a, e1 - 1), 0)];
            w1[u] = (j1a < e1) ? 1.f : 0.f;
        }
        float2 v0[8], v1[8];
        #pragma unroll
        for (int u = 0; u < 8; ++u) {
            v0[u] = __half22float2(*(const __half2*)(sb + (size_t)(unsigned)c0[u]));
            v1[u] = __half22float2(*(const __half2*)(sb + (size_t)(unsigned)c1[u]));
        }
        #pragma unroll
        for (int u = 0; u < 8; ++u) {
            ax0 = fmaf(w0[u], v0[u].x, ax0); ay0 = fmaf(w0[u], v0[u].y, ay0);
            ax1 = fmaf(w1[u], v1[u].x, ax1); ay1 = fmaf(w1[u], v1[u].y, ay1);
        }
    }
    ax0 += __shfl_xor(ax0, 32); ay0 += __shfl_xor(ay0, 32);
    ax1 += __shfl_xor(ax1, 32); ay1 += __shfl_xor(ay1, 32);
    if (ep == 0) {
        if (d0 > 0) {
            float d = dsq[base];
            *(__half2*)((char*)dst + ((size_t)base << 7) + (p << 2)) = __floats2half2_rn(ax0 * d, ay0 * d);
        }
        if (d1 > 0) {
            float d = dsq[base + 1];
            *(__half2*)((char*)dst + ((size_t)(base + 1) << 7) + (p << 2)) = __floats2half2_rn(ax1 * d, ay1 * d);
        }
    }
}

// ---------------- layer-3 SpMV fused into tacc + self term -----------------
__global__ void __launch_bounds__(256) k_spmv3(const __half* __restrict__ src, float* __restrict__ tacc,
                                               const int2* __restrict__ moffs, const int* __restrict__ cols,
                                               const float* __restrict__ dinv, const float* __restrict__ gsc,
                                               const int* __restrict__ uids, const int* __restrict__ iids) {
    int tid = threadIdx.x, lane = tid & 63;
    int t = blockIdx.x * 4 + (tid >> 6);
    if (t >= 2048) return;
    int r = (t < BATCH) ? uids[t] : (N_USER + iids[t - BATCH]);
    int2 se = moffs[r];
    int s = se.x, e = se.y;
    int p = lane & 31, ep = lane >> 5;
    const char* sb = (const char*)src + (p << 2);
    float ax = 0.f, ay = 0.f;
    for (int cb = 0; cb < e - s; cb += 16) {
        int c[8]; float w[8];
        #pragma unroll
        for (int u = 0; u < 8; ++u) {
            int j = s + cb + 2 * u + ep;
            c[u] = cols[max(min(j, e - 1), 0)];
            w[u] = (j < e) ? 1.f : 0.f;
        }
        float2 v[8];
        #pragma unroll
        for (int u = 0; u < 8; ++u)
            v[u] = __half22float2(*(const __half2*)(sb + (size_t)(unsigned)c[u]));
        #pragma unroll
        for (int u = 0; u < 8; ++u) { ax = fmaf(w[u], v[u].x, ax); ay = fmaf(w[u], v[u].y, ay); }
    }
    ax += __shfl_xor(ax, 32);
    ay += __shfl_xor(ay, 32);
    if (ep == 0) {
        float2 self = __half22float2(*(const __half2*)((const char*)src + ((size_t)r << 7) + (p << 2)));
        float di = dinv[r], g = gsc[r];
        float* tp = tacc + (size_t)t * 64 + (p << 1);
        tp[0] += di * ax + g * self.x;
        tp[1] += di * ay + g * self.y;
    }
}

// ---------------- fused X-assembly + MLP -----------------------------------
__global__ void __launch_bounds__(256) k_mlp(const int* __restrict__ aux,
                                             const float* __restrict__ ratef, const float* __restrict__ genderf,
                                             const float* __restrict__ agef, const float* __restrict__ occf,
                                             const float* __restrict__ areaf, const float* __restrict__ tacc,
                                             const float* __restrict__ Xmh, const float* __restrict__ cntf,
                                             const float* __restrict__ W1, const float* __restrict__ b1,
                                             const float* __restrict__ W2, const float* __restrict__ b2,
                                             const float* __restrict__ Wo, const float* __restrict__ bo,
                                             void* __restrict__ out, const void* probe) {
    __shared__ float sx[4][640];
    __shared__ float sh[4][64];
    int isf32 = detect_f32(probe);
    int lane = threadIdx.x & 63, w = threadIdx.x >> 6;
    int b = blockIdx.x * 4 + w;
    const int* arow = aux + (size_t)b * AUX_W;
    float* xr = sx[w];
    xr[0   + lane] = ratef[arow[0] * 64 + lane];
    xr[64  + lane] = Xmh[((size_t)0 * BATCH + b) * 64 + lane] / cntf[0 * BATCH + b];
    xr[128 + lane] = Xmh[((size_t)1 * BATCH + b) * 64 + lane] / cntf[1 * BATCH + b];
    xr[192 + lane] = Xmh[((size_t)2 * BATCH + b) * 64 + lane] / cntf[2 * BATCH + b];
    xr[256 + lane] = genderf[arow[10242] * 64 + lane];
    xr[320 + lane] = agef[arow[10243] * 64 + lane];
    xr[384 + lane] = occf[arow[10244] * 64 + lane];
    xr[448 + lane] = areaf[arow[10245] * 64 + lane];
    xr[512 + lane] = tacc[(size_t)b * 64 + lane] * 0.25f;
    xr[576 + lane] = tacc[(size_t)(BATCH + b) * 64 + lane] * 0.25f;
    float acc = b1[lane];
    #pragma unroll 8
    for (int k = 0; k < 640; ++k) acc += xr[k] * W1[(size_t)k * 64 + lane];
    float h1 = fmaxf(acc, 0.f);
    sh[w][lane] = h1;
    float acc2 = b2[lane];
    #pragma unroll 8
    for (int j = 0; j < 64; ++j) acc2 += sh[w][j] * W2[(size_t)j * 64 + lane];
    float h2 = fmaxf(acc2, 0.f);
    float p = h2 * Wo[lane];
    #pragma unroll
    for (int off = 32; off; off >>= 1) p += __shfl_down(p, off);
    if (lane == 0) {
        float r = p + bo[0];
        if (isf32) ((float*)out)[b] = r;
        else       ((__hip_bfloat16*)out)[b] = __float2bfloat16(r);
    }
}

extern "C" void kernel_launch(void* const* d_in, const int* in_sizes, int n_in,
                              void* d_out, int out_size, void* d_ws, size_t ws_size,
                              hipStream_t stream) {
    const int* aux  = (const int*)d_in[0];
    const int* uids = (const int*)d_in[1];
    const int* iids = (const int*)d_in[2];
    const int* grow = (const int*)d_in[3];
    const int* gcol = (const int*)d_in[4];

    char* p = (char*)d_ws;
    auto alloc = [&](size_t bytes) -> char* {
        char* r = p;
        p += (bytes + 255) / 256 * 256;
        return r;
    };
    // zero-region (one hipMemsetAsync): bucket_tot, Xmh, cntf, moffs2
    int*   bucket_tot  = (int*)alloc(512 * 4);
    float* Xmh         = (float*)alloc((size_t)3 * BATCH * 64 * 4);
    float* cntf        = (float*)alloc((size_t)3 * BATCH * 4);
    int2*  moffs2      = (int2*)alloc((size_t)180224 * 8);
    char*  zero_end    = p;
    int*   bucket_base = (int*)alloc(512 * 4);
    int*   bucketcur   = (int*)alloc(512 * 4);
    int2*  moffs       = (int2*)alloc((size_t)180224 * 8);
    float* dinv        = (float*)alloc((size_t)180224 * 4);
    float* dsq         = (float*)alloc((size_t)180224 * 4);
    float* gsc         = (float*)alloc((size_t)180224 * 4);
    int2*  binned      = (int2*)alloc((size_t)E2 * 8);
    int*   cols        = (int*)alloc((size_t)E2 * 4);
    __half* embA       = (__half*)alloc((size_t)N_NODES * 64 * 2);
    __half* embB       = (__half*)alloc((size_t)N_NODES * 64 * 2);
    float* tacc        = (float*)alloc((size_t)2048 * 64 * 4);
    unsigned short* WtG = (unsigned short*)alloc((size_t)KP_G * 64 * 2);
    unsigned short* WtD = (unsigned short*)alloc((size_t)KP_D * 64 * 2);
    unsigned short* WtA = (unsigned short*)alloc((size_t)KP_A * 64 * 2);
    float* ratef   = (float*)alloc(384 * 4);
    float* genderf = (float*)alloc(128 * 4);
    float* agef    = (float*)alloc(448 * 4);
    float* occf    = (float*)alloc(1344 * 4);
    float* areaf   = (float*)alloc((size_t)217728 * 4);
    float* fc1W    = (float*)alloc((size_t)40960 * 4);
    float* fc1b    = (float*)alloc(64 * 4);
    float* fc2W    = (float*)alloc(4096 * 4);
    float* fc2b    = (float*)alloc(64 * 4);
    float* outW    = (float*)alloc(64 * 4);
    float* outb    = (float*)alloc(4);

    const void* probe = d_in[14];   // user_rel, for inline dtype detect

    // 0. zero accumulators (single contiguous region, DMA)
    hipMemsetAsync(bucket_tot, 0, (size_t)(zero_end - (char*)bucket_tot), stream);

    // 1. fused prep: table cvt + Wt pack + bucket counts
    CvtBatch cb;
    int blk = 0, si = 0;
    auto addseg = [&](const void* s, float* d, int n) {
        cb.seg[si].src = s; cb.seg[si].dst = d; cb.seg[si].n = n; cb.seg[si].blk0 = blk;
        blk += (n + 255) / 256; ++si;
    };
    addseg(d_in[6],  ratef,   384);
    addseg(d_in[10], genderf, 128);
    addseg(d_in[11], agef,    448);
    addseg(d_in[12], occf,    1344);
    addseg(d_in[13], areaf,   217728);
    addseg(d_in[16], fc1W,   40960);
    addseg(d_in[17], fc1b,   64);
    addseg(d_in[18], fc2W,   4096);
    addseg(d_in[19], fc2b,   64);
    addseg(d_in[20], outW,   64);
    addseg(d_in[21], outb,   1);
    for (int i = si; i < 16; ++i) { cb.seg[i].src = nullptr; cb.seg[i].dst = nullptr; cb.seg[i].n = 0; cb.seg[i].blk0 = 0x7fffffff; }
    const int cvtBlks = blk;
    hipLaunchKernelGGL(k_prep, dim3(cvtBlks + WT_BLKS + BCNT_BLKS), dim3(256), 0, stream,
                       cb, cvtBlks, d_in[7], d_in[8], d_in[9], WtG, WtD, WtA, grow, bucket_tot, probe);

    // 2. CSR build
    hipLaunchKernelGGL(k_bscan, dim3(1), dim3(512), 0, stream, bucket_tot, bucket_base, bucketcur);
    hipLaunchKernelGGL(k_p1, dim3((E2 + 4095) / 4096), dim3(256), 0, stream, grow, gcol, bucketcur, binned);
    hipLaunchKernelGGL(k_p2, dim3(NBKT), dim3(256), 0, stream, binned, bucket_base, cols, moffs, dinv, dsq, gsc);

    // 3. fused (long-pole-first): mhgemm + mark + tacc0 + emb cvt
    const int cvtN = (N_NODES * 16 + 255) / 256;
    hipLaunchKernelGGL(k_cvt_fused, dim3(1376 + cvtN), dim3(256), 0, stream,
                       d_in[14], d_in[15], dinv, embA, tacc, uids, iids, cvtN,
                       moffs, cols, moffs2, aux, WtG, WtD, WtA, Xmh, cntf);

    // 4. LightGCN: L1 unmasked; L2 via moffs2 (+fused tacc f1); L3 at T (+self)
    const int spmvN = (N_NODES + 7) / 8;   // row-pair: 8 rows per block
    hipLaunchKernelGGL(k_spmv, dim3(spmvN), dim3(256), 0, stream,
                       embA, embB, moffs, cols, dsq, spmvN, (float*)nullptr, uids, iids, gsc);
    hipLaunchKernelGGL(k_spmv, dim3(spmvN + 512), dim3(256), 0, stream,
                       embB, embA, moffs2, cols, dsq, spmvN, tacc, uids, iids, gsc);
    hipLaunchKernelGGL(k_spmv3, dim3(2048 / 4), dim3(256), 0, stream,
                       embA, tacc, moffs, cols, dinv, gsc, uids, iids);

    // 5. fused X+MLP -> out
    hipLaunchKernelGGL(k_mlp, dim3(BATCH / 4), dim3(256), 0, stream,
                       aux, ratef, genderf, agef, occf, areaf, tacc, Xmh, cntf,
                       fc1W, fc1b, fc2W, fc2b, outW, outb, d_out, probe);
}